// Round 6
// baseline (646.978 us; speedup 1.0000x reference)
//
#include <hip/hip_runtime.h>
#include <hip/hip_bf16.h>
#include <cstdint>

#define T_    4096
#define HID_  2048
#define DH    128
#define NQ_   16
#define NKV_  4
#define QKVW  3072   // 2048 Q + 512 K + 512 V

typedef __attribute__((ext_vector_type(8))) short bf16x8;
typedef __attribute__((ext_vector_type(4))) float f32x4;
typedef __attribute__((ext_vector_type(16))) float f32x16;
typedef __attribute__((ext_vector_type(4))) float f4;
typedef __attribute__((ext_vector_type(4))) short s4;

__device__ __forceinline__ short f2bf(float f) {
  union { float f; unsigned u; } x; x.f = f;
  unsigned r = x.u + 0x7fffu + ((x.u >> 16) & 1u);
  return (short)(r >> 16);
}
__device__ __forceinline__ float bf2f(short s) {
  return __uint_as_float(((unsigned)(unsigned short)s) << 16);
}
__device__ __forceinline__ unsigned pkbf2(float a, float b) {
  union { __hip_bfloat162 h; unsigned u; } c;
  c.h = __float22bfloat162_rn(make_float2(a, b));
  return c.u;
}

__device__ __forceinline__ void gload16(const void* g, void* l) {
  __builtin_amdgcn_global_load_lds(
      (const __attribute__((address_space(1))) unsigned*)g,
      (__attribute__((address_space(3))) unsigned*)l, 16, 0, 0);
}

#define MFMA16(a, b, c) __builtin_amdgcn_mfma_f32_16x16x32_bf16(a, b, c, 0, 0, 0)
#define MFMA32(a, b, c) __builtin_amdgcn_mfma_f32_32x32x16_bf16(a, b, c, 0, 0, 0)

#define Z16 {0.f,0.f,0.f,0.f,0.f,0.f,0.f,0.f,0.f,0.f,0.f,0.f,0.f,0.f,0.f,0.f}
#define SCL2 0.127517432f  // (1/sqrt(128)) * log2(e), folded into Q at RoPE

// ---------------- fp32 -> bf16 conversion ----------------
__global__ void cvtk(const float* __restrict__ s, short* __restrict__ d, int n4) {
  int i = blockIdx.x * blockDim.x + threadIdx.x;
  const int stride = gridDim.x * blockDim.x;
  for (; i < n4; i += stride) {
    f4 v = ((const f4*)s)[i];
    s4 o;
    o[0] = f2bf(v[0]); o[1] = f2bf(v[1]); o[2] = f2bf(v[2]); o[3] = f2bf(v[3]);
    ((s4*)d)[i] = o;
  }
}

// ---------------- GEMM: C = A (MxK) * B^T, B stored (N,K) row-major ----------------
template <int BF16OUT>
__global__ __launch_bounds__(256) void gemm_bt(const short* __restrict__ A,
                                               const short* __restrict__ B,
                                               void* __restrict__ Cp,
                                               int N, int K) {
  __shared__ short lA[128 * 32];
  __shared__ short lB[128 * 32];
  const int tid = threadIdx.x;
  const int lane = tid & 63;
  const int w = tid >> 6;
  const int wr = w >> 1, wc = w & 1;
  const int l15 = lane & 15, l4 = lane >> 4;
  f32x4 acc[4][4];
#pragma unroll
  for (int m = 0; m < 4; m++)
#pragma unroll
    for (int n = 0; n < 4; n++) acc[m][n] = f32x4{0.f, 0.f, 0.f, 0.f};

  const short* Ag = A + (size_t)blockIdx.x * 128 * K;
  const short* Bg = B + (size_t)blockIdx.y * 128 * K;

  for (int kt = 0; kt < K; kt += 32) {
#pragma unroll
    for (int i = 0; i < 2; ++i) {
      const int cb = i * 256 + w * 64;      // wave-uniform chunk base
      const int c = cb + lane;              // chunk of 8 bf16 (16B)
      const int row = c >> 2, eo = (c & 3) << 3;
      gload16(Ag + (size_t)row * K + kt + eo, &lA[cb * 8]);
      gload16(Bg + (size_t)row * K + kt + eo, &lB[cb * 8]);
    }
    __syncthreads();
    bf16x8 af[4], bfr[4];
#pragma unroll
    for (int m = 0; m < 4; m++)
      af[m] = *(const bf16x8*)&lA[(wr * 64 + m * 16 + l15) * 32 + l4 * 8];
#pragma unroll
    for (int n = 0; n < 4; n++)
      bfr[n] = *(const bf16x8*)&lB[(wc * 64 + n * 16 + l15) * 32 + l4 * 8];
#pragma unroll
    for (int m = 0; m < 4; m++)
#pragma unroll
      for (int n = 0; n < 4; n++)
        acc[m][n] = MFMA16(af[m], bfr[n], acc[m][n]);
    __syncthreads();
  }

  const int r0 = blockIdx.x * 128 + wr * 64;
  const int c0 = blockIdx.y * 128 + wc * 64;
#pragma unroll
  for (int m = 0; m < 4; m++)
#pragma unroll
    for (int n = 0; n < 4; n++)
#pragma unroll
      for (int r = 0; r < 4; r++) {
        const int row = r0 + m * 16 + l4 * 4 + r;
        const int col = c0 + n * 16 + l15;
        if (BF16OUT)
          ((short*)Cp)[(size_t)row * N + col] = f2bf(acc[m][n][r]);
        else
          ((float*)Cp)[(size_t)row * N + col] = acc[m][n][r];
      }
}

// ---------------- RoPE (in-place; Q heads additionally pre-scaled by SCL2) ----------------
__global__ void rope_k(short* __restrict__ qkv, const int* __restrict__ pos) {
  const int row = blockIdx.x;
  const int sub = threadIdx.x >> 6;  // 0..3
  const int d = threadIdx.x & 63;
  const int head = blockIdx.y * 4 + sub;  // 0..19 : 16 Q heads then 4 K heads
  const int col0 = (head < NQ_) ? head * DH : HID_ + (head - NQ_) * DH;
  const float scl = (head < NQ_) ? SCL2 : 1.0f;
  short* p = qkv + (size_t)row * QKVW + col0;
  const float fp = (float)pos[row];
  const float freq = fp * powf(10000.0f, -(float)d * (1.0f / 64.0f));
  const float sn = sinf(freq), cs = cosf(freq);
  const float x1 = bf2f(p[d]);
  const float x2 = bf2f(p[d + 64]);
  p[d] = f2bf((x1 * cs - x2 * sn) * scl);
  p[d + 64] = f2bf((x2 * cs + x1 * sn) * scl);
}

// ---------------- causal GQA flash attention (v6: split-KV, 16 waves/CU) ----------------
// 512 blocks x 512 threads, 2 blocks/CU. Block = (kvh, pairi, kv-parity half).
// 8 waves = 4 heads x 2 q-blocks {pairi, 127-pairi} (concurrent; tile needs are
// prefixes so all staged tiles are shared). Each half writes normalized O (bf16)
// + (m,l); merge_k combines the two halves. LDS: 2 x 32KB double buffer.

// prefetch tile tt (kv rows [tt*64, +64)) into 4 regs (512 threads)
#define PRE(tt)                                                                     \
  {                                                                                 \
    const int kv0p = (tt) * 64;                                                     \
    _Pragma("unroll") for (int i = 0; i < 2; i++) {                                 \
      const int idx = i * 512 + tid;                                                \
      const int row = idx >> 4, e = (idx & 15) << 3;                                \
      kreg[i] = *(const bf16x8*)(kbase + (size_t)(kv0p + row) * QKVW + e);          \
    }                                                                               \
    {                                                                               \
      const int rp = tid >> 4, e = (tid & 15) << 3;                                 \
      vreg[0] = *(const bf16x8*)(vbase + (size_t)(kv0p + 2 * rp) * QKVW + e);       \
      vreg[1] = *(const bf16x8*)(vbase + (size_t)(kv0p + 2 * rp + 1) * QKVW + e);   \
    }                                                                               \
  }

// write staged regs into 32KB buffer at bufp (K [64][256B] swz, V^T [128][128B] swz)
#define WRITEBUF(bufp)                                                          \
  {                                                                             \
    char* sK_ = (bufp);                                                         \
    char* sV_ = (bufp) + 16384;                                                 \
    _Pragma("unroll") for (int i = 0; i < 2; i++) {                             \
      const int idx = i * 512 + tid;                                            \
      const int row = idx >> 4, e16 = (idx & 15) << 4;                          \
      const int swz = (((row >> 3) ^ row) & 7) << 4;                            \
      *(bf16x8*)(sK_ + row * 256 + (e16 ^ swz)) = kreg[i];                      \
    }                                                                           \
    {                                                                           \
      const int rp = tid >> 4, e = (tid & 15) << 3;                             \
      _Pragma("unroll") for (int jj = 0; jj < 8; jj++) {                        \
        const int d = e + jj;                                                   \
        const int swz = (((d >> 3) ^ d) & 7) << 4;                              \
        const unsigned pk = ((unsigned)(unsigned short)vreg[0][jj]) |           \
                            (((unsigned)(unsigned short)vreg[1][jj]) << 16);    \
        *(unsigned*)(sV_ + d * 128 + ((rp * 4) ^ swz)) = pk;                    \
      }                                                                         \
    }                                                                           \
  }

__global__ __launch_bounds__(512, 4) void attn_k(const short* __restrict__ qkv,
                                                 short* __restrict__ out0,
                                                 short* __restrict__ out1,
                                                 float2* __restrict__ ml) {
  __shared__ __align__(16) char smem[65536];  // 2 x 32KB double buffer

  const int bid = blockIdx.x;
  const int item = (bid & 7) * 64 + (bid >> 3);  // XCD-chunked, bijective on 512
  const int kvh = item >> 7;
  const int r_ = item & 127;
  const int pairi = r_ >> 1;
  const int half = r_ & 1;
  const int tid = threadIdx.x, lane = tid & 63, w = tid >> 6;
  const int head = w & 3, which = w >> 2;
  const int hi = lane >> 5, l31 = lane & 31;
  const int h = kvh * 4 + head;
  const int qb = which ? (127 - pairi) : pairi;
  const int nt = qb / 2 + 1;                    // this wave's tile count
  const int nthi = (127 - pairi) / 2 + 1;       // block's staged range (hi qb)
  const int ns = (nthi - half + 1) >> 1;        // # staged tiles of my parity
  const int qrow0 = qb * 32;
  const int myq = qrow0 + l31;

  const short* kbase = qkv + HID_ + kvh * DH;
  const short* vbase = qkv + HID_ + NKV_ * DH + kvh * DH;

  bf16x8 qf[8];
  {
    const short* qp = qkv + (size_t)myq * QKVW + h * DH + hi * 8;
#pragma unroll
    for (int c = 0; c < 8; c++) qf[c] = *(const bf16x8*)(qp + c * 16);
  }
  f32x16 o[4] = {Z16, Z16, Z16, Z16};
  float m = -3e38f, l = 0.f;

  bf16x8 kreg[2], vreg[2];
  PRE(half)
  WRITEBUF(smem)
  if (ns > 1) PRE(half + 2)

  for (int j = 0; j < ns; ++j) {
    __syncthreads();  // publishes buf[j&1]; prev compute on buf[(j+1)&1] done
    if (j + 1 < ns) {
      WRITEBUF(smem + ((j + 1) & 1) * 32768)
      if (j + 2 < ns) PRE(half + 2 * (j + 2))
    }
    const char* bK = smem + (j & 1) * 32768;
    const char* bV = bK + 16384;
    const int tj = half + 2 * j;

    if (tj < nt) {
      const int kv0 = tj * 64;
      // ---- S^T = K Q^T : two 32x32 tiles over kv rows (log2 domain) ----
      f32x16 s0 = Z16, s1 = Z16;
      const int sw0 = (((l31 >> 3) ^ l31) & 7) << 4;
      const int r1 = 32 + l31;
      const int sw1 = (((r1 >> 3) ^ r1) & 7) << 4;
      __builtin_amdgcn_s_setprio(1);
#pragma unroll
      for (int c = 0; c < 8; c++) {
        const int co = c * 32 + hi * 16;
        const bf16x8 k0 = *(const bf16x8*)(bK + l31 * 256 + (co ^ sw0));
        const bf16x8 k1 = *(const bf16x8*)(bK + r1 * 256 + (co ^ sw1));
        s0 = MFMA32(k0, qf[c], s0);
        s1 = MFMA32(k1, qf[c], s1);
      }
      __builtin_amdgcn_s_setprio(0);
      // ---- in-register online softmax (lane owns q-row l31) ----
      float sv0[16], sv1[16];
      if (tj == nt - 1) {
#pragma unroll
        for (int r = 0; r < 16; r++) {
          const int kk = (r & 3) + 8 * (r >> 2) + 4 * hi;
          sv0[r] = (kv0 + kk <= myq) ? s0[r] : -1e30f;
          sv1[r] = (kv0 + 32 + kk <= myq) ? s1[r] : -1e30f;
        }
      } else {
#pragma unroll
        for (int r = 0; r < 16; r++) {
          sv0[r] = s0[r];
          sv1[r] = s1[r];
        }
      }
      float mx[8];
#pragma unroll
      for (int r = 0; r < 8; r++)
        mx[r] = fmaxf(fmaxf(sv0[r], sv0[r + 8]), fmaxf(sv1[r], sv1[r + 8]));
#pragma unroll
      for (int st = 4; st > 0; st >>= 1)
#pragma unroll
        for (int r = 0; r < 4; r++)
          if (r < st) mx[r] = fmaxf(mx[r], mx[r + st]);
      float pm = fmaxf(mx[0], __shfl_xor(mx[0], 32));
      if (__any(pm > m + 11.5f)) {  // defer-max (T13)
        const float mn = fmaxf(m, pm);
        const float al = exp2f(m - mn);
        m = mn;
        l *= al;
#pragma unroll
        for (int r = 0; r < 16; r++) {
          const float ar = __shfl(al, (r & 3) + 8 * (r >> 2) + 4 * hi);
#pragma unroll
          for (int dt = 0; dt < 4; dt++) o[dt][r] *= ar;
        }
      }
      float pv0[16], pv1[16];
#pragma unroll
      for (int r = 0; r < 16; r++) {
        pv0[r] = exp2f(sv0[r] - m);
        pv1[r] = exp2f(sv1[r] - m);
      }
      float sum[8];
#pragma unroll
      for (int r = 0; r < 8; r++)
        sum[r] = (pv0[r] + pv0[r + 8]) + (pv1[r] + pv1[r + 8]);
#pragma unroll
      for (int st = 4; st > 0; st >>= 1)
#pragma unroll
        for (int r = 0; r < 4; r++)
          if (r < st) sum[r] = sum[r] + sum[r + st];
      l += sum[0] + __shfl_xor(sum[0], 32);

      // ---- P -> bf16 A-frags (cvt_pk + half-exchange), PV ----
      unsigned W0[8], W1[8];
#pragma unroll
      for (int i = 0; i < 8; i++) {
        W0[i] = pkbf2(pv0[2 * i], pv0[2 * i + 1]);
        W1[i] = pkbf2(pv1[2 * i], pv1[2 * i + 1]);
      }
#pragma unroll
      for (int kt = 0; kt < 2; kt++) {
#pragma unroll
        for (int hc = 0; hc < 2; hc++) {
          const int base2 = hc * 4;
          const unsigned a = kt ? W1[base2] : W0[base2];
          const unsigned c2 = kt ? W1[base2 + 1] : W0[base2 + 1];
          const unsigned b = kt ? W1[base2 + 2] : W0[base2 + 2];
          const unsigned d2 = kt ? W1[base2 + 3] : W0[base2 + 3];
          const unsigned as = __shfl_xor(a, 32);
          const unsigned cs = __shfl_xor(c2, 32);
          const unsigned bs = __shfl_xor(b, 32);
          const unsigned ds = __shfl_xor(d2, 32);
          union { unsigned u[4]; bf16x8 v; } fr;
          fr.u[0] = hi ? bs : a;
          fr.u[1] = hi ? ds : c2;
          fr.u[2] = hi ? b : as;
          fr.u[3] = hi ? d2 : cs;
          const int ko = kt * 64 + hc * 32 + hi * 16;
          __builtin_amdgcn_s_setprio(1);
#pragma unroll
          for (int dt = 0; dt < 4; dt++) {
            const int row = dt * 32 + l31;
            const int swz = (((row >> 3) ^ row) & 7) << 4;
            const bf16x8 vf = *(const bf16x8*)(bV + row * 128 + (ko ^ swz));
            o[dt] = MFMA32(fr.v, vf, o[dt]);
          }
          __builtin_amdgcn_s_setprio(0);
        }
      }
    }
  }

  // ---- epilogue: write normalized partial O + (m,l) ----
  const float ri = (l > 0.f) ? 1.0f / l : 0.f;
  short* dst = half ? out1 : out0;
#pragma unroll
  for (int r = 0; r < 16; r++) {
    const int q = (r & 3) + 8 * (r >> 2) + 4 * hi;
    const float rr = __shfl(ri, q);
#pragma unroll
    for (int dt = 0; dt < 4; dt++)
      dst[(size_t)(qrow0 + q) * HID_ + h * DH + dt * 32 + l31] = f2bf(o[dt][r] * rr);
  }
  if (lane < 32)
    ml[((size_t)half * T_ + qrow0 + lane) * NQ_ + h] = make_float2(m, l);
}

// ---------------- split-KV merge: out0 = norm-combine(out0, out1) ----------------
__global__ __launch_bounds__(256) void merge_k(short* __restrict__ out0,
                                               const short* __restrict__ out1,
                                               const float2* __restrict__ ml) {
  const int gid = blockIdx.x * 256 + threadIdx.x;  // < T*HID/8
  const int row = gid >> 8;
  const int chunk = gid & 255;
  const int headi = chunk >> 4;
  const float2 a = ml[(size_t)row * NQ_ + headi];
  const float2 b = ml[((size_t)T_ + row) * NQ_ + headi];
  const float M = fmaxf(a.x, b.x);
  const float w0 = exp2f(a.x - M) * a.y;
  const float w1 = exp2f(b.x - M) * b.y;
  const float rs = 1.0f / (w0 + w1);
  const float a0 = w0 * rs, a1 = w1 * rs;
  const bf16x8 v0 = *(const bf16x8*)(out0 + (size_t)gid * 8);
  const bf16x8 v1 = *(const bf16x8*)(out1 + (size_t)gid * 8);
  bf16x8 ov;
#pragma unroll
  for (int i = 0; i < 8; i++)
    ov[i] = f2bf(a0 * bf2f(v0[i]) + a1 * bf2f(v1[i]));
  *(bf16x8*)(out0 + (size_t)gid * 8) = ov;
}

extern "C" void kernel_launch(void* const* d_in, const int* in_sizes, int n_in,
                              void* d_out, int out_size, void* d_ws, size_t ws_size,
                              hipStream_t stream) {
  const float* hs = (const float*)d_in[0];
  const float* wq = (const float*)d_in[1];
  const float* wk = (const float*)d_in[2];
  const float* wv = (const float*)d_in[3];
  const float* wo = (const float*)d_in[4];
  const int* pos = (const int*)d_in[5];
  float* out = (float*)d_out;

  const size_t SZ_HS = (size_t)T_ * HID_;
  const size_t SZ_WQ = (size_t)HID_ * HID_;
  const size_t SZ_WK = (size_t)(NKV_ * DH) * HID_;
  const size_t SZ_W1 = (size_t)QKVW * HID_;
  const size_t SZ_QKV = (size_t)T_ * QKVW;

  short* hs_bf = (short*)d_ws;
  short* w1_bf = hs_bf + SZ_HS;
  short* wo_bf = w1_bf + SZ_W1;
  short* qkv = wo_bf + SZ_WQ;
  short* attn = qkv + SZ_QKV;

  // regions reused after the QKV GEMM (hs_bf/w1_bf are dead then):
  short* part1 = hs_bf;               // half1 normalized O, T*HID bf16 (16MB)
  float2* ml = (float2*)w1_bf;        // [2][T][NQ] (m,l), 1MB

  cvtk<<<1024, 256, 0, stream>>>(hs, hs_bf, (int)(SZ_HS / 4));
  cvtk<<<1024, 256, 0, stream>>>(wq, w1_bf, (int)(SZ_WQ / 4));
  cvtk<<<256, 256, 0, stream>>>(wk, w1_bf + SZ_WQ, (int)(SZ_WK / 4));
  cvtk<<<256, 256, 0, stream>>>(wv, w1_bf + SZ_WQ + SZ_WK, (int)(SZ_WK / 4));
  cvtk<<<1024, 256, 0, stream>>>(wo, wo_bf, (int)(SZ_WQ / 4));

  // QKV projection: (4096 x 2048) * (3072 x 2048)^T -> qkv bf16
  gemm_bt<1><<<dim3(T_ / 128, QKVW / 128), 256, 0, stream>>>(hs_bf, w1_bf, qkv, QKVW, HID_);

  // RoPE on Q (16 heads, pre-scaled) + K (4 heads), in place
  rope_k<<<dim3(T_, 5), 256, 0, stream>>>(qkv, pos);

  // causal GQA flash attention, split-KV halves -> attn (half0) + part1 (half1)
  attn_k<<<dim3(512), 512, 0, stream>>>(qkv, attn, part1, ml);

  // combine halves -> attn
  merge_k<<<dim3((T_ * HID_ / 8) / 256), 256, 0, stream>>>(attn, part1, ml);

  // output projection: (4096 x 2048) * (2048 x 2048)^T -> fp32 out
  gemm_bt<0><<<dim3(T_ / 128, HID_ / 128), 256, 0, stream>>>(attn, wo_bf, out, HID_, HID_);
}

// Round 7
// 332.498 us; speedup vs baseline: 1.9458x; 1.9458x over previous
//
#include <hip/hip_runtime.h>
#include <hip/hip_bf16.h>
#include <cstdint>

#define T_    4096
#define HID_  2048
#define DH    128
#define NQ_   16
#define NKV_  4
#define QKVW  3072   // 2048 Q + 512 K + 512 V

typedef __attribute__((ext_vector_type(8))) short bf16x8;
typedef __attribute__((ext_vector_type(4))) float f32x4;
typedef __attribute__((ext_vector_type(16))) float f32x16;
typedef __attribute__((ext_vector_type(4))) float f4;
typedef __attribute__((ext_vector_type(4))) short s4;

__device__ __forceinline__ short f2bf(float f) {
  union { float f; unsigned u; } x; x.f = f;
  unsigned r = x.u + 0x7fffu + ((x.u >> 16) & 1u);
  return (short)(r >> 16);
}
__device__ __forceinline__ float bf2f(short s) {
  return __uint_as_float(((unsigned)(unsigned short)s) << 16);
}
__device__ __forceinline__ unsigned pkbf2(float a, float b) {
  union { __hip_bfloat162 h; unsigned u; } c;
  c.h = __float22bfloat162_rn(make_float2(a, b));
  return c.u;
}

__device__ __forceinline__ void gload16(const void* g, void* l) {
  __builtin_amdgcn_global_load_lds(
      (const __attribute__((address_space(1))) unsigned*)g,
      (__attribute__((address_space(3))) unsigned*)l, 16, 0, 0);
}

#define MFMA16(a, b, c) __builtin_amdgcn_mfma_f32_16x16x32_bf16(a, b, c, 0, 0, 0)
#define MFMA32(a, b, c) __builtin_amdgcn_mfma_f32_32x32x16_bf16(a, b, c, 0, 0, 0)

#define Z16 {0.f,0.f,0.f,0.f,0.f,0.f,0.f,0.f,0.f,0.f,0.f,0.f,0.f,0.f,0.f,0.f}
#define SCL2 0.127517432f  // (1/sqrt(128)) * log2(e), folded into Q at RoPE

// ---------------- fp32 -> bf16 conversion ----------------
__global__ void cvtk(const float* __restrict__ s, short* __restrict__ d, int n4) {
  int i = blockIdx.x * blockDim.x + threadIdx.x;
  const int stride = gridDim.x * blockDim.x;
  for (; i < n4; i += stride) {
    f4 v = ((const f4*)s)[i];
    s4 o;
    o[0] = f2bf(v[0]); o[1] = f2bf(v[1]); o[2] = f2bf(v[2]); o[3] = f2bf(v[3]);
    ((s4*)d)[i] = o;
  }
}

// ---------------- GEMM: C = A (MxK) * B^T, B stored (N,K) row-major ----------------
template <int BF16OUT>
__global__ __launch_bounds__(256) void gemm_bt(const short* __restrict__ A,
                                               const short* __restrict__ B,
                                               void* __restrict__ Cp,
                                               int N, int K) {
  __shared__ short lA[128 * 32];
  __shared__ short lB[128 * 32];
  const int tid = threadIdx.x;
  const int lane = tid & 63;
  const int w = tid >> 6;
  const int wr = w >> 1, wc = w & 1;
  const int l15 = lane & 15, l4 = lane >> 4;
  f32x4 acc[4][4];
#pragma unroll
  for (int m = 0; m < 4; m++)
#pragma unroll
    for (int n = 0; n < 4; n++) acc[m][n] = f32x4{0.f, 0.f, 0.f, 0.f};

  const short* Ag = A + (size_t)blockIdx.x * 128 * K;
  const short* Bg = B + (size_t)blockIdx.y * 128 * K;

  for (int kt = 0; kt < K; kt += 32) {
#pragma unroll
    for (int i = 0; i < 2; ++i) {
      const int cb = i * 256 + w * 64;      // wave-uniform chunk base
      const int c = cb + lane;              // chunk of 8 bf16 (16B)
      const int row = c >> 2, eo = (c & 3) << 3;
      gload16(Ag + (size_t)row * K + kt + eo, &lA[cb * 8]);
      gload16(Bg + (size_t)row * K + kt + eo, &lB[cb * 8]);
    }
    __syncthreads();
    bf16x8 af[4], bfr[4];
#pragma unroll
    for (int m = 0; m < 4; m++)
      af[m] = *(const bf16x8*)&lA[(wr * 64 + m * 16 + l15) * 32 + l4 * 8];
#pragma unroll
    for (int n = 0; n < 4; n++)
      bfr[n] = *(const bf16x8*)&lB[(wc * 64 + n * 16 + l15) * 32 + l4 * 8];
#pragma unroll
    for (int m = 0; m < 4; m++)
#pragma unroll
      for (int n = 0; n < 4; n++)
        acc[m][n] = MFMA16(af[m], bfr[n], acc[m][n]);
    __syncthreads();
  }

  const int r0 = blockIdx.x * 128 + wr * 64;
  const int c0 = blockIdx.y * 128 + wc * 64;
#pragma unroll
  for (int m = 0; m < 4; m++)
#pragma unroll
    for (int n = 0; n < 4; n++)
#pragma unroll
      for (int r = 0; r < 4; r++) {
        const int row = r0 + m * 16 + l4 * 4 + r;
        const int col = c0 + n * 16 + l15;
        if (BF16OUT)
          ((short*)Cp)[(size_t)row * N + col] = f2bf(acc[m][n][r]);
        else
          ((float*)Cp)[(size_t)row * N + col] = acc[m][n][r];
      }
}

// ---------------- RoPE (in-place; Q heads additionally pre-scaled by SCL2) ----------------
__global__ void rope_k(short* __restrict__ qkv, const int* __restrict__ pos) {
  const int row = blockIdx.x;
  const int sub = threadIdx.x >> 6;  // 0..3
  const int d = threadIdx.x & 63;
  const int head = blockIdx.y * 4 + sub;  // 0..19 : 16 Q heads then 4 K heads
  const int col0 = (head < NQ_) ? head * DH : HID_ + (head - NQ_) * DH;
  const float scl = (head < NQ_) ? SCL2 : 1.0f;
  short* p = qkv + (size_t)row * QKVW + col0;
  const float fp = (float)pos[row];
  const float freq = fp * powf(10000.0f, -(float)d * (1.0f / 64.0f));
  const float sn = sinf(freq), cs = cosf(freq);
  const float x1 = bf2f(p[d]);
  const float x2 = bf2f(p[d + 64]);
  p[d] = f2bf((x1 * cs - x2 * sn) * scl);
  p[d + 64] = f2bf((x2 * cs + x1 * sn) * scl);
}

// ---------------- causal GQA flash attention (v7) ----------------
// v5 structure (256 blocks x 512 thr, 8 waves = 4 heads x 2 KV-splits, LDS
// dbuf, serial q-pairing) + V^T stored with kv-slot permutation sigma(kv) =
// swap bits 2<->3, which makes the PV A-fragment equal the lane's OWN packed
// P words (W[4hc..4hc+3]) for both hi halves -> the 16 shfl_xor(32) + 16
// selects per tile vanish. + s_setprio around MFMA clusters (T5).

// prefetch supertile j (even kv0=j*128, odd +64) into 8 regs (512 threads)
#define PRE(j)                                                                      \
  {                                                                                 \
    const int kv0e = (j) * 128, kv0o = (j) * 128 + 64;                              \
    _Pragma("unroll") for (int i = 0; i < 2; i++) {                                 \
      const int idx = i * 512 + tid;                                                \
      const int row = idx >> 4, e = (idx & 15) << 3;                                \
      kre[i] = *(const bf16x8*)(kbase + (size_t)(kv0e + row) * QKVW + e);           \
      kro[i] = *(const bf16x8*)(kbase + (size_t)(kv0o + row) * QKVW + e);           \
    }                                                                               \
    {                                                                               \
      const int rp = tid >> 4, e = (tid & 15) << 3;                                 \
      vre[0] = *(const bf16x8*)(vbase + (size_t)(kv0e + 2 * rp) * QKVW + e);        \
      vre[1] = *(const bf16x8*)(vbase + (size_t)(kv0e + 2 * rp + 1) * QKVW + e);    \
      vro[0] = *(const bf16x8*)(vbase + (size_t)(kv0o + 2 * rp) * QKVW + e);        \
      vro[1] = *(const bf16x8*)(vbase + (size_t)(kv0o + 2 * rp + 1) * QKVW + e);    \
    }                                                                               \
  }

// write staged regs into buffer at bufp (swizzled; V pair-col permuted b1<->b2)
#define WRITEBUF(bufp)                                                          \
  {                                                                             \
    char* sKe_ = (bufp);                                                        \
    char* sKo_ = (bufp) + 16384;                                                \
    char* sVe_ = (bufp) + 32768;                                                \
    char* sVo_ = (bufp) + 49152;                                                \
    _Pragma("unroll") for (int i = 0; i < 2; i++) {                             \
      const int idx = i * 512 + tid;                                            \
      const int row = idx >> 4, e16 = (idx & 15) << 4;                          \
      const int swz = (((row >> 3) ^ row) & 7) << 4;                            \
      *(bf16x8*)(sKe_ + row * 256 + (e16 ^ swz)) = kre[i];                      \
      *(bf16x8*)(sKo_ + row * 256 + (e16 ^ swz)) = kro[i];                      \
    }                                                                           \
    {                                                                           \
      const int rp = tid >> 4, e = (tid & 15) << 3;                             \
      const int rp2 = (rp & ~6) | ((rp & 2) << 1) | ((rp & 4) >> 1);            \
      _Pragma("unroll") for (int jj = 0; jj < 8; jj++) {                        \
        const int d = e + jj;                                                   \
        const int swz = (((d >> 3) ^ d) & 7) << 4;                              \
        const unsigned pe = ((unsigned)(unsigned short)vre[0][jj]) |            \
                            (((unsigned)(unsigned short)vre[1][jj]) << 16);     \
        const unsigned po = ((unsigned)(unsigned short)vro[0][jj]) |            \
                            (((unsigned)(unsigned short)vro[1][jj]) << 16);     \
        *(unsigned*)(sVe_ + d * 128 + ((rp2 * 4) ^ swz)) = pe;                  \
        *(unsigned*)(sVo_ + d * 128 + ((rp2 * 4) ^ swz)) = po;                  \
      }                                                                         \
    }                                                                           \
  }

__global__ __launch_bounds__(512) void attn_k(const short* __restrict__ qkv,
                                              short* __restrict__ aout) {
  // two 64KB staging buffers (double-buffer) + 2KB m/l exchange
  __shared__ __align__(16) char smem[133120];
  float* ml = (float*)(smem + 131072);  // [head][sp][2][32]

  const int lin = blockIdx.x;
  const int rl = (lin & 7) * 32 + (lin >> 3);  // XCD-chunked remap (bijective on 256)
  const int kvh = rl >> 6;
  const int pairi = rl & 63;
  const int tid = threadIdx.x, lane = tid & 63, w = tid >> 6;
  const int head = w & 3, sp = w >> 2;
  const int hi = lane >> 5, l31 = lane & 31;
  const int h = kvh * 4 + head;

  const short* kbase = qkv + HID_ + kvh * DH;
  const short* vbase = qkv + HID_ + NKV_ * DH + kvh * DH;
  const int spoff = sp ? 16384 : 0;

  for (int hf = 0; hf < 2; ++hf) {
    const int qb = hf ? (127 - pairi) : pairi;
    const int qrow0 = qb * 32;
    const int ntiles = qb / 2 + 1;
    const int nsuper = (ntiles + 1) >> 1;
    const int myq = qrow0 + l31;

    bf16x8 qf[8];
    {
      const short* qp = qkv + (size_t)myq * QKVW + h * DH + hi * 8;
#pragma unroll
      for (int c = 0; c < 8; c++) qf[c] = *(const bf16x8*)(qp + c * 16);
    }
    f32x16 o[4] = {Z16, Z16, Z16, Z16};
    float m = -3e38f, l = 0.f;

    bf16x8 kre[2], kro[2], vre[2], vro[2];
    // prologue: fill buf0, prefetch supertile 1
    PRE(0)
    WRITEBUF(smem)
    if (nsuper > 1) PRE(1)

    for (int j = 0; j < nsuper; ++j) {
      __syncthreads();  // publishes buf[j&1]; prev compute on buf[(j+1)&1] done
      if (j + 1 < nsuper) {
        WRITEBUF(smem + ((j + 1) & 1) * 65536)  // overlaps compute below
        if (j + 2 < nsuper) PRE(j + 2)
      }
      const char* base = smem + (j & 1) * 65536;
      const char* bK = base + spoff;
      const char* bV = base + 32768 + spoff;

      const int t = 2 * j + sp;
      if (t < ntiles) {
        const int kv0 = t * 64;
        // ---- S^T = K Q^T : two 32x32 tiles over kv rows (log2 domain) ----
        f32x16 s0 = Z16, s1 = Z16;
        const int sw0 = (((l31 >> 3) ^ l31) & 7) << 4;
        const int r1 = 32 + l31;
        const int sw1 = (((r1 >> 3) ^ r1) & 7) << 4;
        __builtin_amdgcn_s_setprio(1);
#pragma unroll
        for (int c = 0; c < 8; c++) {
          const int co = c * 32 + hi * 16;
          const bf16x8 k0 = *(const bf16x8*)(bK + l31 * 256 + (co ^ sw0));
          const bf16x8 k1 = *(const bf16x8*)(bK + r1 * 256 + (co ^ sw1));
          s0 = MFMA32(k0, qf[c], s0);
          s1 = MFMA32(k1, qf[c], s1);
        }
        __builtin_amdgcn_s_setprio(0);
        // ---- in-register online softmax ----
        float sv0[16], sv1[16];
        if (t == ntiles - 1) {
#pragma unroll
          for (int r = 0; r < 16; r++) {
            const int kk = (r & 3) + 8 * (r >> 2) + 4 * hi;
            sv0[r] = (kv0 + kk <= myq) ? s0[r] : -1e30f;
            sv1[r] = (kv0 + 32 + kk <= myq) ? s1[r] : -1e30f;
          }
        } else {
#pragma unroll
          for (int r = 0; r < 16; r++) {
            sv0[r] = s0[r];
            sv1[r] = s1[r];
          }
        }
        float mx[8];
#pragma unroll
        for (int r = 0; r < 8; r++)
          mx[r] = fmaxf(fmaxf(sv0[r], sv0[r + 8]), fmaxf(sv1[r], sv1[r + 8]));
#pragma unroll
        for (int st = 4; st > 0; st >>= 1)
#pragma unroll
          for (int r = 0; r < 4; r++)
            if (r < st) mx[r] = fmaxf(mx[r], mx[r + st]);
        float pm = fmaxf(mx[0], __shfl_xor(mx[0], 32));
        if (__any(pm > m + 11.5f)) {  // defer-max (T13)
          const float mn = fmaxf(m, pm);
          const float al = exp2f(m - mn);
          m = mn;
          l *= al;
#pragma unroll
          for (int r = 0; r < 16; r++) {
            const float ar = __shfl(al, (r & 3) + 8 * (r >> 2) + 4 * hi);
#pragma unroll
            for (int dt = 0; dt < 4; dt++) o[dt][r] *= ar;
          }
        }
        float pv0[16], pv1[16];
#pragma unroll
        for (int r = 0; r < 16; r++) {
          pv0[r] = exp2f(sv0[r] - m);
          pv1[r] = exp2f(sv1[r] - m);
        }
        float sum[8];
#pragma unroll
        for (int r = 0; r < 8; r++)
          sum[r] = (pv0[r] + pv0[r + 8]) + (pv1[r] + pv1[r + 8]);
#pragma unroll
        for (int st = 4; st > 0; st >>= 1)
#pragma unroll
          for (int r = 0; r < 4; r++)
            if (r < st) sum[r] = sum[r] + sum[r + st];
        l += sum[0] + __shfl_xor(sum[0], 32);

        // ---- P -> bf16 A-frags: direct pack (V rows are sigma-permuted) ----
        unsigned W0[8], W1[8];
#pragma unroll
        for (int i = 0; i < 8; i++) {
          W0[i] = pkbf2(pv0[2 * i], pv0[2 * i + 1]);
          W1[i] = pkbf2(pv1[2 * i], pv1[2 * i + 1]);
        }
#pragma unroll
        for (int kt = 0; kt < 2; kt++) {
#pragma unroll
          for (int hc = 0; hc < 2; hc++) {
            union { unsigned u[4]; bf16x8 v; } fr;
#pragma unroll
            for (int mm = 0; mm < 4; mm++)
              fr.u[mm] = kt ? W1[hc * 4 + mm] : W0[hc * 4 + mm];
            const int ko = kt * 64 + hc * 32 + hi * 16;
            __builtin_amdgcn_s_setprio(1);
#pragma unroll
            for (int dt = 0; dt < 4; dt++) {
              const int row = dt * 32 + l31;
              const int swz = (((row >> 3) ^ row) & 7) << 4;
              const bf16x8 vf = *(const bf16x8*)(bV + row * 128 + (ko ^ swz));
              o[dt] = MFMA32(fr.v, vf, o[dt]);
            }
            __builtin_amdgcn_s_setprio(0);
          }
        }
      }
    }

    // ---- merge the two KV-splits of each head, write out ----
    if (lane < 32) {
      ml[((head * 2 + sp) * 2) * 32 + lane] = m;
      ml[((head * 2 + sp) * 2 + 1) * 32 + lane] = l;
    }
    __syncthreads();  // also: all compute reads of staging buffers done
    const float mo = ml[((head * 2 + (1 - sp)) * 2) * 32 + l31];
    const float lo = ml[((head * 2 + (1 - sp)) * 2 + 1) * 32 + l31];
    const float M = fmaxf(m, mo);
    const float aown = exp2f(m - M);
    const float ltot = l * aown + lo * exp2f(mo - M);
#pragma unroll
    for (int r = 0; r < 16; r++) {
      const float ar = __shfl(aown, (r & 3) + 8 * (r >> 2) + 4 * hi);
#pragma unroll
      for (int dt = 0; dt < 4; dt++) o[dt][r] *= ar;
    }
    float* Ob = (float*)smem + head * 4096;  // [32 q][128 d], reuses buf0
    if (sp == 1) {
#pragma unroll
      for (int r = 0; r < 16; r++) {
        const int q = (r & 3) + 8 * (r >> 2) + 4 * hi;
#pragma unroll
        for (int dt = 0; dt < 4; dt++) Ob[q * 128 + dt * 32 + l31] = o[dt][r];
      }
    }
    __syncthreads();
    if (sp == 0) {
      const float ri = 1.0f / ltot;
#pragma unroll
      for (int r = 0; r < 16; r++) {
        const float rr = __shfl(ri, (r & 3) + 8 * (r >> 2) + 4 * hi);
        const int q = (r & 3) + 8 * (r >> 2) + 4 * hi;
#pragma unroll
        for (int dt = 0; dt < 4; dt++) {
          const float val = (o[dt][r] + Ob[q * 128 + dt * 32 + l31]) * rr;
          aout[(size_t)(qrow0 + q) * HID_ + h * DH + dt * 32 + l31] = f2bf(val);
        }
      }
    }
    __syncthreads();  // Ob reads done before next hf's prologue WRITEBUF
  }
}

extern "C" void kernel_launch(void* const* d_in, const int* in_sizes, int n_in,
                              void* d_out, int out_size, void* d_ws, size_t ws_size,
                              hipStream_t stream) {
  const float* hs = (const float*)d_in[0];
  const float* wq = (const float*)d_in[1];
  const float* wk = (const float*)d_in[2];
  const float* wv = (const float*)d_in[3];
  const float* wo = (const float*)d_in[4];
  const int* pos = (const int*)d_in[5];
  float* out = (float*)d_out;

  const size_t SZ_HS = (size_t)T_ * HID_;
  const size_t SZ_WQ = (size_t)HID_ * HID_;
  const size_t SZ_WK = (size_t)(NKV_ * DH) * HID_;
  const size_t SZ_W1 = (size_t)QKVW * HID_;
  const size_t SZ_QKV = (size_t)T_ * QKVW;

  short* hs_bf = (short*)d_ws;
  short* w1_bf = hs_bf + SZ_HS;
  short* wo_bf = w1_bf + SZ_W1;
  short* qkv = wo_bf + SZ_WQ;
  short* attn = qkv + SZ_QKV;

  cvtk<<<1024, 256, 0, stream>>>(hs, hs_bf, (int)(SZ_HS / 4));
  cvtk<<<1024, 256, 0, stream>>>(wq, w1_bf, (int)(SZ_WQ / 4));
  cvtk<<<256, 256, 0, stream>>>(wk, w1_bf + SZ_WQ, (int)(SZ_WK / 4));
  cvtk<<<256, 256, 0, stream>>>(wv, w1_bf + SZ_WQ + SZ_WK, (int)(SZ_WK / 4));
  cvtk<<<1024, 256, 0, stream>>>(wo, wo_bf, (int)(SZ_WQ / 4));

  // QKV projection: (4096 x 2048) * (3072 x 2048)^T -> qkv bf16
  gemm_bt<1><<<dim3(T_ / 128, QKVW / 128), 256, 0, stream>>>(hs_bf, w1_bf, qkv, QKVW, HID_);

  // RoPE on Q (16 heads, pre-scaled) + K (4 heads), in place
  rope_k<<<dim3(T_, 5), 256, 0, stream>>>(qkv, pos);

  // causal GQA flash attention -> attn bf16 (T, 2048)
  attn_k<<<dim3(256), 512, 0, stream>>>(qkv, attn);

  // output projection: (4096 x 2048) * (2048 x 2048)^T -> fp32 out
  gemm_bt<0><<<dim3(T_ / 128, HID_ / 128), 256, 0, stream>>>(attn, wo_bf, out, HID_, HID_);
}